// Round 6
// baseline (733.064 us; speedup 1.0000x reference)
//
#include <hip/hip_runtime.h>

// ws float layout:
//  [0:6)   sum1   [6:12)  sumsq1
//  [12:28) sum2   [28:44) sumsq2
//  [44:50) sc1    [50:56) sh1
//  [56:72) sc2    [72:88) sh2
#define WS_SUM1 0
#define WS_SQ1  6
#define WS_SUM2 12
#define WS_SQ2  28
#define WS_SC1  44
#define WS_SH1  50
#define WS_SC2  56
#define WS_SH2  72
#define WS_NFLOATS 88

#define PST 145        // per-image LDS stride: 12x12 padded image + 1
#define POOL_CST 28    // per-channel pooled stride (25 -> pad 28, 16B-aligned)
#define POOL_IST 172   // per-image pooled stride (6*28=168 -> pad 172: 12-bank skew)

__device__ __forceinline__ float wave_sum(float v) {
#pragma unroll
  for (int off = 32; off > 0; off >>= 1) v += __shfl_down(v, off, 64);
  return v;
}

// Stage 16 zero-padded images (12x12, pad=2 border) into LDS.
// Block layout: 256 threads = 16 images x 16 threads. Fully coalesced x read.
__device__ __forceinline__ void stage_x(const float* __restrict__ x,
                                        float* xl, int blk) {
  const int tid = threadIdx.x;
  for (int i = tid; i < 16 * PST; i += 256) xl[i] = 0.f;
  __syncthreads();
  const float4 v = reinterpret_cast<const float4*>(x)[blk * 256 + tid];
  const int imgl = tid >> 4;
  const int f = (tid & 15) * 4;
  const int row = f >> 3, col = f & 7;
  float* dst = xl + imgl * PST + (row + 2) * 12 + (col + 2);
  dst[0] = v.x; dst[1] = v.y; dst[2] = v.z; dst[3] = v.w;
  __syncthreads();
}

// Phase 1 (cooperative): conv1+BN1+ReLU+meanpool2 -> pool[6][25] per image in
// LDS, each pooled value computed exactly once. Thread l handles pooled
// positions l and l+16 (if <25) of its image.
__device__ __forceinline__ void pooled_front_coop(
    const float* xl, float* pool, const float* __restrict__ w1,
    const float* __restrict__ b1, const float* wsf) {
  const int tid = threadIdx.x;
  const int imgl = tid >> 4, l16 = tid & 15;
  const float* ibase = xl + imgl * PST;
  float* pbase = pool + imgl * POOL_IST;

#pragma unroll
  for (int k2 = 0; k2 < 2; ++k2) {
    const int p = l16 + 16 * k2;
    if (p < 25) {
      const int r = p / 5, s = p % 5;
      const float* wb = ibase + (2 * r) * 12 + 2 * s;
      float X[16];
#pragma unroll
      for (int a = 0; a < 4; ++a)
#pragma unroll
        for (int b = 0; b < 4; ++b) X[a * 4 + b] = wb[a * 12 + b];
#pragma unroll
      for (int i = 0; i < 16; ++i) asm volatile("" : "+v"(X[i]));
#pragma unroll
      for (int c = 0; c < 6; ++c) {
        const float bc = b1[c];
        const float sc = wsf[WS_SC1 + c];
        const float sh = wsf[WS_SH1 + c];
        float acc = 0.f;
#pragma unroll
        for (int di = 0; di < 2; ++di) {
#pragma unroll
          for (int dj = 0; dj < 2; ++dj) {
            float z = bc;
#pragma unroll
            for (int u = 0; u < 3; ++u)
#pragma unroll
              for (int v = 0; v < 3; ++v)
                z = fmaf(w1[c * 9 + u * 3 + v], X[(di + u) * 4 + dj + v], z);
            acc += fmaxf(fmaf(z, sc, sh), 0.f);
          }
        }
        pbase[c * POOL_CST + p] = 0.25f * acc;
      }
    }
  }
}

// Phase 2 (channel-per-lane): lane o in [0,16) computes raw conv2 outputs
// yp[16 positions] for channel o of its image. w2 row is per-lane VGPR data.
__device__ __forceinline__ void conv2_lane(
    const float* pool, const float* __restrict__ w2,
    const float* __restrict__ b2, float yp[16]) {
  const int tid = threadIdx.x;
  const int imgl = tid >> 4, o = tid & 15;
  const float* pbase = pool + imgl * POOL_IST;

  float4 w2v[6];
#pragma unroll
  for (int c = 0; c < 6; ++c)
    w2v[c] = reinterpret_cast<const float4*>(w2)[o * 6 + c];
  const float yb = b2[o];
#pragma unroll
  for (int p = 0; p < 16; ++p) yp[p] = yb;

#pragma unroll
  for (int c = 0; c < 6; ++c) {
    float pc[25];
    const float4* pr = reinterpret_cast<const float4*>(pbase + c * POOL_CST);
#pragma unroll
    for (int qq = 0; qq < 6; ++qq) {
      float4 v = pr[qq];
      pc[qq * 4 + 0] = v.x; pc[qq * 4 + 1] = v.y;
      pc[qq * 4 + 2] = v.z; pc[qq * 4 + 3] = v.w;
    }
    pc[24] = pbase[c * POOL_CST + 24];
#pragma unroll
    for (int i = 0; i < 25; ++i) asm volatile("" : "+v"(pc[i]));
    const float w00 = w2v[c].x, w01 = w2v[c].y;
    const float w10 = w2v[c].z, w11 = w2v[c].w;
#pragma unroll
    for (int i2 = 0; i2 < 4; ++i2) {
#pragma unroll
      for (int j2 = 0; j2 < 4; ++j2) {
        float acc = yp[i2 * 4 + j2];
        acc = fmaf(w00, pc[i2 * 5 + j2], acc);
        acc = fmaf(w01, pc[i2 * 5 + j2 + 1], acc);
        acc = fmaf(w10, pc[(i2 + 1) * 5 + j2], acc);
        acc = fmaf(w11, pc[(i2 + 1) * 5 + j2 + 1], acc);
        yp[i2 * 4 + j2] = acc;
      }
    }
  }
}

// ---------------- Kernel A: conv1 raw-output statistics ----------------
__global__ __launch_bounds__(256) void k_stats1(
    const float* __restrict__ x, const float* __restrict__ w1,
    const float* __restrict__ b1, float* ws) {
  __shared__ float xl[16 * PST];
  __shared__ float red[4][12];
  stage_x(x, xl, blockIdx.x);

  const int tid = threadIdx.x;
  const float* base = xl + (tid >> 4) * PST;
  float sum[6], sq[6];
#pragma unroll
  for (int c = 0; c < 6; ++c) { sum[c] = 0.f; sq[c] = 0.f; }

#pragma unroll 1
  for (int p = tid & 15; p < 100; p += 16) {
    const int i = p / 10, j = p % 10;
    const float* pb = base + i * 12 + j;
    float t0 = pb[0],  t1 = pb[1],  t2 = pb[2];
    float t3 = pb[12], t4 = pb[13], t5 = pb[14];
    float t6 = pb[24], t7 = pb[25], t8 = pb[26];
#pragma unroll
    for (int c = 0; c < 6; ++c) {
      float y = b1[c];
      y = fmaf(w1[c * 9 + 0], t0, y); y = fmaf(w1[c * 9 + 1], t1, y);
      y = fmaf(w1[c * 9 + 2], t2, y); y = fmaf(w1[c * 9 + 3], t3, y);
      y = fmaf(w1[c * 9 + 4], t4, y); y = fmaf(w1[c * 9 + 5], t5, y);
      y = fmaf(w1[c * 9 + 6], t6, y); y = fmaf(w1[c * 9 + 7], t7, y);
      y = fmaf(w1[c * 9 + 8], t8, y);
      sum[c] += y;
      sq[c] = fmaf(y, y, sq[c]);
    }
  }

  const int wid = tid >> 6, lane = tid & 63;
#pragma unroll
  for (int c = 0; c < 6; ++c) {
    const float s = wave_sum(sum[c]);
    const float q = wave_sum(sq[c]);
    if (lane == 0) { red[wid][c] = s; red[wid][6 + c] = q; }
  }
  __syncthreads();
  if (tid < 12) {
    const float tot = red[0][tid] + red[1][tid] + red[2][tid] + red[3][tid];
    atomicAdd(&ws[tid < 6 ? WS_SUM1 + tid : WS_SQ1 + tid - 6], tot);
  }
}

// ---------------- fold kernels: BN stats -> (sc, sh) in ws ----------------
__global__ void k_fold1(const float* __restrict__ g1,
                        const float* __restrict__ be1, float* ws, float inv_n) {
  const int c = threadIdx.x;
  if (c < 6) {
    const float mean = ws[WS_SUM1 + c] * inv_n;
    const float var  = ws[WS_SQ1 + c] * inv_n - mean * mean;
    const float sc   = g1[c] * rsqrtf(var + 1e-5f);
    ws[WS_SC1 + c] = sc;
    ws[WS_SH1 + c] = be1[c] - mean * sc;
  }
}

__global__ void k_fold2(const float* __restrict__ g2,
                        const float* __restrict__ be2, float* ws, float inv_n) {
  const int c = threadIdx.x;
  if (c < 16) {
    const float mean = ws[WS_SUM2 + c] * inv_n;
    const float var  = ws[WS_SQ2 + c] * inv_n - mean * mean;
    const float sc   = g2[c] * rsqrtf(var + 1e-5f);
    ws[WS_SC2 + c] = sc;
    ws[WS_SH2 + c] = be2[c] - mean * sc;
  }
}

// ---------------- Kernel B: conv2 output statistics ----------------
__global__ __launch_bounds__(256) void k_stats2(
    const float* __restrict__ x, const float* __restrict__ w1,
    const float* __restrict__ b1, const float* __restrict__ w2,
    const float* __restrict__ b2, float* ws) {
  __shared__ float xl[16 * PST];
  __shared__ float pool[16 * POOL_IST];
  __shared__ float red[4][32];
  stage_x(x, xl, blockIdx.x);

  pooled_front_coop(xl, pool, w1, b1, ws);
  __syncthreads();

  float yp[16];
  conv2_lane(pool, w2, b2, yp);

  float s = 0.f, q = 0.f;
#pragma unroll
  for (int p = 0; p < 16; ++p) { s += yp[p]; q = fmaf(yp[p], yp[p], q); }
  // reduce across the 4 images of this wave (lanes o, o+16, o+32, o+48)
  s += __shfl_xor(s, 16, 64); s += __shfl_xor(s, 32, 64);
  q += __shfl_xor(q, 16, 64); q += __shfl_xor(q, 32, 64);

  const int tid = threadIdx.x, wid = tid >> 6, lane = tid & 63;
  if (lane < 16) { red[wid][lane] = s; red[wid][16 + lane] = q; }
  __syncthreads();
  if (tid < 32) {
    const float tot = red[0][tid] + red[1][tid] + red[2][tid] + red[3][tid];
    atomicAdd(&ws[tid < 16 ? WS_SUM2 + tid : WS_SQ2 + tid - 16], tot);
  }
}

// ---------------- Kernel C: full forward ----------------
__global__ __launch_bounds__(256) void k_final(
    const float* __restrict__ x, const float* __restrict__ w1,
    const float* __restrict__ b1, const float* __restrict__ w2,
    const float* __restrict__ b2, const float* __restrict__ fw1,
    const float* __restrict__ fb1, const float* __restrict__ fw2,
    const float* __restrict__ fb2, const float* __restrict__ fw3,
    const float* __restrict__ fb3, const float* ws,
    float* __restrict__ out) {
  __shared__ float xl[16 * PST];
  __shared__ float pool[16 * POOL_IST];
  __shared__ float lds_h[16 * 68];
  __shared__ float lds_a1[16 * 33];
  __shared__ float lds_a2[16 * 17];

  stage_x(x, xl, blockIdx.x);
  pooled_front_coop(xl, pool, w1, b1, ws);
  __syncthreads();

  float yp[16];
  conv2_lane(pool, w2, b2, yp);

  const int tid = threadIdx.x;
  const int imgl = tid >> 4, o = tid & 15;

  // BN2 + ReLU + meanpool2: lane o accumulates its 4 flattened h entries
  const float sc2 = ws[WS_SC2 + o], sh2 = ws[WS_SH2 + o];
  float hq[4] = {0.f, 0.f, 0.f, 0.f};
#pragma unroll
  for (int i2 = 0; i2 < 4; ++i2)
#pragma unroll
    for (int j2 = 0; j2 < 4; ++j2)
      hq[(i2 >> 1) * 2 + (j2 >> 1)] +=
          fmaxf(fmaf(yp[i2 * 4 + j2], sc2, sh2), 0.f);
  float4 hv4;
  hv4.x = 0.25f * hq[0]; hv4.y = 0.25f * hq[1];
  hv4.z = 0.25f * hq[2]; hv4.w = 0.25f * hq[3];
  *reinterpret_cast<float4*>(lds_h + imgl * 68 + o * 4) = hv4;
  __syncthreads();

  // FC1: lane al computes outputs {al, al+16}; fw1 rows per-lane from global
  const int al = o;
  const float* hrow = lds_h + imgl * 68;
  const bool has2 = (al + 16) < 30;
  float acc0 = fb1[al];
  float acc1 = has2 ? fb1[al + 16] : 0.f;
  const float4* fa = reinterpret_cast<const float4*>(fw1 + al * 64);
  const float4* fb = reinterpret_cast<const float4*>(fw1 + (has2 ? (al + 16) * 64 : 0));
#pragma unroll
  for (int kk = 0; kk < 16; ++kk) {
    const float4 hv = *reinterpret_cast<const float4*>(hrow + kk * 4);
    const float4 wa = fa[kk];
    const float4 wb = fb[kk];
    acc0 = fmaf(wa.x, hv.x, acc0); acc0 = fmaf(wa.y, hv.y, acc0);
    acc0 = fmaf(wa.z, hv.z, acc0); acc0 = fmaf(wa.w, hv.w, acc0);
    acc1 = fmaf(wb.x, hv.x, acc1); acc1 = fmaf(wb.y, hv.y, acc1);
    acc1 = fmaf(wb.z, hv.z, acc1); acc1 = fmaf(wb.w, hv.w, acc1);
  }
  lds_a1[imgl * 33 + al] = fmaxf(acc0, 0.f);
  if (has2) lds_a1[imgl * 33 + al + 16] = fmaxf(acc1, 0.f);
  __syncthreads();

  // FC2
  if (al < 15) {
    float acc = fb2[al];
#pragma unroll 1
    for (int j = 0; j < 30; ++j)
      acc = fmaf(fw2[al * 30 + j], lds_a1[imgl * 33 + j], acc);
    lds_a2[imgl * 17 + al] = fmaxf(acc, 0.f);
  }
  __syncthreads();

  // FC3 + store
  if (al < 10) {
    float acc = fb3[al];
#pragma unroll 1
    for (int j = 0; j < 15; ++j)
      acc = fmaf(fw3[al * 15 + j], lds_a2[imgl * 17 + j], acc);
    out[(size_t)(blockIdx.x * 16 + imgl) * 10 + al] = acc;
  }
}

extern "C" void kernel_launch(void* const* d_in, const int* in_sizes, int n_in,
                              void* d_out, int out_size, void* d_ws, size_t ws_size,
                              hipStream_t stream) {
  (void)n_in; (void)out_size; (void)ws_size;
  const float* x   = (const float*)d_in[0];
  const float* w1  = (const float*)d_in[1];
  const float* b1  = (const float*)d_in[2];
  const float* g1  = (const float*)d_in[3];
  const float* be1 = (const float*)d_in[4];
  const float* w2  = (const float*)d_in[5];
  const float* b2  = (const float*)d_in[6];
  const float* g2  = (const float*)d_in[7];
  const float* be2 = (const float*)d_in[8];
  const float* fw1 = (const float*)d_in[9];
  const float* fb1 = (const float*)d_in[10];
  const float* fw2 = (const float*)d_in[11];
  const float* fb2 = (const float*)d_in[12];
  const float* fw3 = (const float*)d_in[13];
  const float* fb3 = (const float*)d_in[14];
  float* out = (float*)d_out;
  float* ws  = (float*)d_ws;

  const int Btot = in_sizes[0] / 64;  // 131072; % 16 == 0
  const float inv_n1 = 1.0f / ((float)Btot * 100.0f);
  const float inv_n2 = 1.0f / ((float)Btot * 16.0f);
  const int grid = Btot / 16;

  hipMemsetAsync(ws, 0, WS_NFLOATS * sizeof(float), stream);

  k_stats1<<<grid, 256, 0, stream>>>(x, w1, b1, ws);
  k_fold1<<<1, 64, 0, stream>>>(g1, be1, ws, inv_n1);
  k_stats2<<<grid, 256, 0, stream>>>(x, w1, b1, w2, b2, ws);
  k_fold2<<<1, 64, 0, stream>>>(g2, be2, ws, inv_n2);
  k_final<<<grid, 256, 0, stream>>>(x, w1, b1, w2, b2,
                                    fw1, fb1, fw2, fb2, fw3, fb3, ws, out);
}

// Round 7
// 485.796 us; speedup vs baseline: 1.5090x; 1.5090x over previous
//
#include <hip/hip_runtime.h>

// ws float layout:
//  [0:6)    sum1    [6:12)   sumsq1
//  [12:28)  sum2    [28:44)  sumsq2
//  [44:50)  sc1     [50:56)  sh1
//  [56:72)  sc2     [72:88)  sh2
//  [88:142) w1s (w1*sc1)     [142:148) b1s (b1*sc1+sh1)
#define WS_SUM1 0
#define WS_SQ1  6
#define WS_SUM2 12
#define WS_SQ2  28
#define WS_SC1  44
#define WS_SH1  50
#define WS_SC2  56
#define WS_SH2  72
#define WS_W1S  88
#define WS_B1S  142
#define WS_NFLOATS 148

#define PST 145        // per-image LDS stride: 12x12 padded image + 1
#define POOL_CST 28    // per-channel pooled stride (25 -> pad 28)
#define POOL_IST 172   // per-image pooled stride (6*28=168 -> pad 172)

__device__ __forceinline__ float wave_sum(float v) {
#pragma unroll
  for (int off = 32; off > 0; off >>= 1) v += __shfl_down(v, off, 64);
  return v;
}

// Stage 16 zero-padded images (12x12, pad=2 border) into LDS.
__device__ __forceinline__ void stage_x(const float* __restrict__ x,
                                        float* xl, int blk) {
  const int tid = threadIdx.x;
  for (int i = tid; i < 16 * PST; i += 256) xl[i] = 0.f;
  __syncthreads();
  const float4 v = reinterpret_cast<const float4*>(x)[blk * 256 + tid];
  const int imgl = tid >> 4;
  const int f = (tid & 15) * 4;
  const int row = f >> 3, col = f & 7;
  float* dst = xl + imgl * PST + (row + 2) * 12 + (col + 2);
  dst[0] = v.x; dst[1] = v.y; dst[2] = v.z; dst[3] = v.w;
  __syncthreads();
}

// Cooperative front: conv1 (BN1 pre-folded into w1s/b1s) + ReLU + meanpool2
// -> pool[6][25] per image in LDS; each pooled value computed exactly once.
// Thread l16 handles pooled positions l16 and l16+16 (if < 25).
__device__ __forceinline__ void pooled_front_coop(const float* xl, float* pool,
                                                  const float* wsf) {
  const int tid = threadIdx.x;
  const int imgl = tid >> 4, l16 = tid & 15;
  const float* ibase = xl + imgl * PST;
  float* pbase = pool + imgl * POOL_IST;

#pragma unroll
  for (int k2 = 0; k2 < 2; ++k2) {
    const int p = l16 + 16 * k2;
    if (p < 25) {
      const int r = p / 5, s = p % 5;
      const float* wb = ibase + (2 * r) * 12 + 2 * s;
      float X[16];
#pragma unroll
      for (int a = 0; a < 4; ++a)
#pragma unroll
        for (int b = 0; b < 4; ++b) X[a * 4 + b] = wb[a * 12 + b];
#pragma unroll
      for (int i = 0; i < 16; ++i) asm volatile("" : "+v"(X[i]));
#pragma unroll
      for (int c = 0; c < 6; ++c) {
        const float bc = wsf[WS_B1S + c];
        float acc = 0.f;
#pragma unroll
        for (int di = 0; di < 2; ++di) {
#pragma unroll
          for (int dj = 0; dj < 2; ++dj) {
            float z = bc;
#pragma unroll
            for (int u = 0; u < 3; ++u)
#pragma unroll
              for (int v = 0; v < 3; ++v)
                z = fmaf(wsf[WS_W1S + c * 9 + u * 3 + v],
                         X[(di + u) * 4 + dj + v], z);
            acc += fmaxf(z, 0.f);
          }
        }
        pbase[c * POOL_CST + p] = 0.25f * acc;
      }
    }
  }
}

// Channel-per-lane conv2: lane o computes raw conv2 outputs yp[16 positions]
// for channel o of its image. w2 row in per-lane VGPRs; pooled values read
// directly from LDS as operands (no pinned preload -> no spills).
__device__ __forceinline__ void conv2_lane(const float* pool,
                                           const float* __restrict__ w2,
                                           const float* __restrict__ b2,
                                           float yp[16]) {
  const int tid = threadIdx.x;
  const int imgl = tid >> 4, o = tid & 15;
  const float* pbase = pool + imgl * POOL_IST;

  float4 w2v[6];
#pragma unroll
  for (int c = 0; c < 6; ++c)
    w2v[c] = reinterpret_cast<const float4*>(w2)[o * 6 + c];
  const float yb = b2[o];
#pragma unroll
  for (int p = 0; p < 16; ++p) yp[p] = yb;

#pragma unroll
  for (int c = 0; c < 6; ++c) {
    const float* pcb = pbase + c * POOL_CST;
    const float w00 = w2v[c].x, w01 = w2v[c].y;
    const float w10 = w2v[c].z, w11 = w2v[c].w;
#pragma unroll
    for (int i2 = 0; i2 < 4; ++i2) {
#pragma unroll
      for (int j2 = 0; j2 < 4; ++j2) {
        float acc = yp[i2 * 4 + j2];
        acc = fmaf(w00, pcb[i2 * 5 + j2], acc);
        acc = fmaf(w01, pcb[i2 * 5 + j2 + 1], acc);
        acc = fmaf(w10, pcb[(i2 + 1) * 5 + j2], acc);
        acc = fmaf(w11, pcb[(i2 + 1) * 5 + j2 + 1], acc);
        yp[i2 * 4 + j2] = acc;
      }
    }
  }
}

// ---------------- Kernel A: conv1 raw-output statistics ----------------
__global__ __launch_bounds__(256) void k_stats1(
    const float* __restrict__ x, const float* __restrict__ w1,
    const float* __restrict__ b1, float* ws) {
  __shared__ float xl[16 * PST];
  __shared__ float red[4][12];
  stage_x(x, xl, blockIdx.x);

  const int tid = threadIdx.x;
  const float* base = xl + (tid >> 4) * PST;
  float sum[6], sq[6];
#pragma unroll
  for (int c = 0; c < 6; ++c) { sum[c] = 0.f; sq[c] = 0.f; }

#pragma unroll 1
  for (int p = tid & 15; p < 100; p += 16) {
    const int i = p / 10, j = p % 10;
    const float* pb = base + i * 12 + j;
    float t0 = pb[0],  t1 = pb[1],  t2 = pb[2];
    float t3 = pb[12], t4 = pb[13], t5 = pb[14];
    float t6 = pb[24], t7 = pb[25], t8 = pb[26];
#pragma unroll
    for (int c = 0; c < 6; ++c) {
      float y = b1[c];
      y = fmaf(w1[c * 9 + 0], t0, y); y = fmaf(w1[c * 9 + 1], t1, y);
      y = fmaf(w1[c * 9 + 2], t2, y); y = fmaf(w1[c * 9 + 3], t3, y);
      y = fmaf(w1[c * 9 + 4], t4, y); y = fmaf(w1[c * 9 + 5], t5, y);
      y = fmaf(w1[c * 9 + 6], t6, y); y = fmaf(w1[c * 9 + 7], t7, y);
      y = fmaf(w1[c * 9 + 8], t8, y);
      sum[c] += y;
      sq[c] = fmaf(y, y, sq[c]);
    }
  }

  const int wid = tid >> 6, lane = tid & 63;
#pragma unroll
  for (int c = 0; c < 6; ++c) {
    const float s = wave_sum(sum[c]);
    const float q = wave_sum(sq[c]);
    if (lane == 0) { red[wid][c] = s; red[wid][6 + c] = q; }
  }
  __syncthreads();
  if (tid < 12) {
    const float tot = red[0][tid] + red[1][tid] + red[2][tid] + red[3][tid];
    atomicAdd(&ws[tid < 6 ? WS_SUM1 + tid : WS_SQ1 + tid - 6], tot);
  }
}

// -------- fold kernels: BN stats -> (sc, sh) and folded conv1 weights ------
__global__ void k_fold1(const float* __restrict__ g1,
                        const float* __restrict__ be1,
                        const float* __restrict__ w1,
                        const float* __restrict__ b1, float* ws, float inv_n) {
  const int c = threadIdx.x;
  if (c < 6) {
    const float mean = ws[WS_SUM1 + c] * inv_n;
    const float var  = ws[WS_SQ1 + c] * inv_n - mean * mean;
    const float sc   = g1[c] * rsqrtf(var + 1e-5f);
    ws[WS_SC1 + c] = sc;
    ws[WS_SH1 + c] = be1[c] - mean * sc;
  }
  __syncthreads();
  if (c < 54) ws[WS_W1S + c] = w1[c] * ws[WS_SC1 + c / 9];
  if (c < 6)  ws[WS_B1S + c] = fmaf(b1[c], ws[WS_SC1 + c], ws[WS_SH1 + c]);
}

__global__ void k_fold2(const float* __restrict__ g2,
                        const float* __restrict__ be2, float* ws, float inv_n) {
  const int c = threadIdx.x;
  if (c < 16) {
    const float mean = ws[WS_SUM2 + c] * inv_n;
    const float var  = ws[WS_SQ2 + c] * inv_n - mean * mean;
    const float sc   = g2[c] * rsqrtf(var + 1e-5f);
    ws[WS_SC2 + c] = sc;
    ws[WS_SH2 + c] = be2[c] - mean * sc;
  }
}

// ---------------- Kernel B: conv2 output statistics ----------------
__global__ __launch_bounds__(256, 2) void k_stats2(
    const float* __restrict__ x, const float* __restrict__ w2,
    const float* __restrict__ b2, float* ws) {
  __shared__ float xl[16 * PST];
  __shared__ float pool[16 * POOL_IST];
  __shared__ float red[4][32];
  stage_x(x, xl, blockIdx.x);

  pooled_front_coop(xl, pool, ws);
  __syncthreads();

  float yp[16];
  conv2_lane(pool, w2, b2, yp);

  float s = 0.f, q = 0.f;
#pragma unroll
  for (int p = 0; p < 16; ++p) { s += yp[p]; q = fmaf(yp[p], yp[p], q); }
  s += __shfl_xor(s, 16, 64); s += __shfl_xor(s, 32, 64);
  q += __shfl_xor(q, 16, 64); q += __shfl_xor(q, 32, 64);

  const int tid = threadIdx.x, wid = tid >> 6, lane = tid & 63;
  if (lane < 16) { red[wid][lane] = s; red[wid][16 + lane] = q; }
  __syncthreads();
  if (tid < 32) {
    const float tot = red[0][tid] + red[1][tid] + red[2][tid] + red[3][tid];
    atomicAdd(&ws[tid < 16 ? WS_SUM2 + tid : WS_SQ2 + tid - 16], tot);
  }
}

// ---------------- Kernel C: full forward ----------------
__global__ __launch_bounds__(256, 2) void k_final(
    const float* __restrict__ x, const float* __restrict__ w2,
    const float* __restrict__ b2, const float* __restrict__ fw1,
    const float* __restrict__ fb1, const float* __restrict__ fw2,
    const float* __restrict__ fb2, const float* __restrict__ fw3,
    const float* __restrict__ fb3, float* ws, float* __restrict__ out) {
  __shared__ float xl[16 * PST];
  __shared__ float pool[16 * POOL_IST];
  __shared__ float lds_h[16 * 68];
  __shared__ float lds_a1[16 * 33];
  __shared__ float lds_a2[16 * 17];

  stage_x(x, xl, blockIdx.x);
  pooled_front_coop(xl, pool, ws);
  __syncthreads();

  float yp[16];
  conv2_lane(pool, w2, b2, yp);

  const int tid = threadIdx.x;
  const int imgl = tid >> 4, o = tid & 15;

  // BN2 + ReLU + meanpool2: lane o accumulates its 4 flattened h entries
  const float sc2 = ws[WS_SC2 + o], sh2 = ws[WS_SH2 + o];
  float hq[4] = {0.f, 0.f, 0.f, 0.f};
#pragma unroll
  for (int i2 = 0; i2 < 4; ++i2)
#pragma unroll
    for (int j2 = 0; j2 < 4; ++j2)
      hq[(i2 >> 1) * 2 + (j2 >> 1)] +=
          fmaxf(fmaf(yp[i2 * 4 + j2], sc2, sh2), 0.f);
  float4 hv4;
  hv4.x = 0.25f * hq[0]; hv4.y = 0.25f * hq[1];
  hv4.z = 0.25f * hq[2]; hv4.w = 0.25f * hq[3];
  *reinterpret_cast<float4*>(lds_h + imgl * 68 + o * 4) = hv4;
  __syncthreads();

  // FC1: lane al computes outputs {al, al+16}; fw1 rows per-lane from global
  const int al = o;
  const float* hrow = lds_h + imgl * 68;
  const bool has2 = (al + 16) < 30;
  float acc0 = fb1[al];
  float acc1 = has2 ? fb1[al + 16] : 0.f;
  const float4* fa = reinterpret_cast<const float4*>(fw1 + al * 64);
  const float4* fb = reinterpret_cast<const float4*>(fw1 + (has2 ? (al + 16) * 64 : 0));
#pragma unroll
  for (int kk = 0; kk < 16; ++kk) {
    const float4 hv = *reinterpret_cast<const float4*>(hrow + kk * 4);
    const float4 wa = fa[kk];
    const float4 wb = fb[kk];
    acc0 = fmaf(wa.x, hv.x, acc0); acc0 = fmaf(wa.y, hv.y, acc0);
    acc0 = fmaf(wa.z, hv.z, acc0); acc0 = fmaf(wa.w, hv.w, acc0);
    acc1 = fmaf(wb.x, hv.x, acc1); acc1 = fmaf(wb.y, hv.y, acc1);
    acc1 = fmaf(wb.z, hv.z, acc1); acc1 = fmaf(wb.w, hv.w, acc1);
  }
  lds_a1[imgl * 33 + al] = fmaxf(acc0, 0.f);
  if (has2) lds_a1[imgl * 33 + al + 16] = fmaxf(acc1, 0.f);
  __syncthreads();

  // FC2
  if (al < 15) {
    float acc = fb2[al];
#pragma unroll 1
    for (int j = 0; j < 30; ++j)
      acc = fmaf(fw2[al * 30 + j], lds_a1[imgl * 33 + j], acc);
    lds_a2[imgl * 17 + al] = fmaxf(acc, 0.f);
  }
  __syncthreads();

  // FC3 + store
  if (al < 10) {
    float acc = fb3[al];
#pragma unroll 1
    for (int j = 0; j < 15; ++j)
      acc = fmaf(fw3[al * 15 + j], lds_a2[imgl * 17 + j], acc);
    out[(size_t)(blockIdx.x * 16 + imgl) * 10 + al] = acc;
  }
}

extern "C" void kernel_launch(void* const* d_in, const int* in_sizes, int n_in,
                              void* d_out, int out_size, void* d_ws, size_t ws_size,
                              hipStream_t stream) {
  (void)n_in; (void)out_size; (void)ws_size;
  const float* x   = (const float*)d_in[0];
  const float* w1  = (const float*)d_in[1];
  const float* b1  = (const float*)d_in[2];
  const float* g1  = (const float*)d_in[3];
  const float* be1 = (const float*)d_in[4];
  const float* w2  = (const float*)d_in[5];
  const float* b2  = (const float*)d_in[6];
  const float* g2  = (const float*)d_in[7];
  const float* be2 = (const float*)d_in[8];
  const float* fw1 = (const float*)d_in[9];
  const float* fb1 = (const float*)d_in[10];
  const float* fw2 = (const float*)d_in[11];
  const float* fb2 = (const float*)d_in[12];
  const float* fw3 = (const float*)d_in[13];
  const float* fb3 = (const float*)d_in[14];
  float* out = (float*)d_out;
  float* ws  = (float*)d_ws;

  const int Btot = in_sizes[0] / 64;  // 131072; % 16 == 0
  const float inv_n1 = 1.0f / ((float)Btot * 100.0f);
  const float inv_n2 = 1.0f / ((float)Btot * 16.0f);
  const int grid = Btot / 16;

  hipMemsetAsync(ws, 0, WS_NFLOATS * sizeof(float), stream);

  k_stats1<<<grid, 256, 0, stream>>>(x, w1, b1, ws);
  k_fold1<<<1, 64, 0, stream>>>(g1, be1, w1, b1, ws, inv_n1);
  k_stats2<<<grid, 256, 0, stream>>>(x, w2, b2, ws);
  k_fold2<<<1, 64, 0, stream>>>(g2, be2, ws, inv_n2);
  k_final<<<grid, 256, 0, stream>>>(x, w2, b2,
                                    fw1, fb1, fw2, fb2, fw3, fb3, ws, out);
}

// Round 8
// 471.154 us; speedup vs baseline: 1.5559x; 1.0311x over previous
//
#include <hip/hip_runtime.h>

// ws float layout:
//  [0:6)    sum1    [6:12)   sumsq1
//  [12:28)  sum2    [28:44)  sumsq2
//  [44:50)  sc1     [50:56)  sh1
//  [56:72)  sc2     [72:88)  sh2
//  [88:142) w1s (w1*sc1)     [142:148) b1s (b1*sc1+sh1)
//  [128*?.. ) -- pooled-front scratch starts at float 128 (16B aligned)
#define WS_SUM1 0
#define WS_SQ1  6
#define WS_SUM2 12
#define WS_SQ2  28
#define WS_SC1  44
#define WS_SH1  50
#define WS_SC2  56
#define WS_SH2  72
#define WS_W1S  88
#define WS_B1S  142
#define WS_NFLOATS 148
#define WS_POOL_OFF 128  // pool region offset in floats (after 512B header... header is 148 floats; pool starts at 160 for safety)
#define WS_POOL_START 160  // floats; 640B, 16B aligned

#define PST 145        // per-image LDS stride: 12x12 padded image + 1
#define POOL_CST 36    // per-channel pooled stride (5x5 map, row stride 6)
#define POOL_IST 220   // per-image pooled stride: 6*36+4; %32=28 -> bank skew

__device__ __forceinline__ float wave_sum(float v) {
#pragma unroll
  for (int off = 32; off > 0; off >>= 1) v += __shfl_down(v, off, 64);
  return v;
}

// Stage 16 zero-padded images (12x12, pad=2 border) into LDS.
__device__ __forceinline__ void stage_x(const float* __restrict__ x,
                                        float* xl, int blk) {
  const int tid = threadIdx.x;
  for (int i = tid; i < 16 * PST; i += 256) xl[i] = 0.f;
  __syncthreads();
  const float4 v = reinterpret_cast<const float4*>(x)[blk * 256 + tid];
  const int imgl = tid >> 4;
  const int f = (tid & 15) * 4;
  const int row = f >> 3, col = f & 7;
  float* dst = xl + imgl * PST + (row + 2) * 12 + (col + 2);
  dst[0] = v.x; dst[1] = v.y; dst[2] = v.z; dst[3] = v.w;
  __syncthreads();
}

// Cooperative front: conv1 (BN1 pre-folded into w1s/b1s) + ReLU + meanpool2
// -> pool[6][5x5 (stride 6)] per image in LDS; each value computed once.
__device__ __forceinline__ void pooled_front_coop(const float* xl, float* pool,
                                                  const float* wsf) {
  const int tid = threadIdx.x;
  const int imgl = tid >> 4, l16 = tid & 15;
  const float* ibase = xl + imgl * PST;
  float* pbase = pool + imgl * POOL_IST;

#pragma unroll
  for (int k2 = 0; k2 < 2; ++k2) {
    const int p = l16 + 16 * k2;
    if (p < 25) {
      const int r = p / 5, s = p % 5;
      const float* wb = ibase + (2 * r) * 12 + 2 * s;
      float X[16];
#pragma unroll
      for (int a = 0; a < 4; ++a)
#pragma unroll
        for (int b = 0; b < 4; ++b) X[a * 4 + b] = wb[a * 12 + b];
#pragma unroll
      for (int i = 0; i < 16; ++i) asm volatile("" : "+v"(X[i]));
#pragma unroll
      for (int c = 0; c < 6; ++c) {
        const float bc = wsf[WS_B1S + c];
        float acc = 0.f;
#pragma unroll
        for (int di = 0; di < 2; ++di) {
#pragma unroll
          for (int dj = 0; dj < 2; ++dj) {
            float z = bc;
#pragma unroll
            for (int u = 0; u < 3; ++u)
#pragma unroll
              for (int v = 0; v < 3; ++v)
                z = fmaf(wsf[WS_W1S + c * 9 + u * 3 + v],
                         X[(di + u) * 4 + dj + v], z);
            acc += fmaxf(z, 0.f);
          }
        }
        pbase[c * POOL_CST + r * 6 + s] = 0.25f * acc;
      }
    }
  }
}

__device__ __forceinline__ void load6(const float* p, float r[6]) {
  const float2* q = reinterpret_cast<const float2*>(p);
  const float2 a = q[0], b = q[1], c = q[2];
  r[0] = a.x; r[1] = a.y; r[2] = b.x; r[3] = b.y; r[4] = c.x; r[5] = c.y;
}

// Channel-per-lane conv2, rolling 2-row stencil: each pooled value is read
// from LDS exactly once (as float2), used from registers.
__device__ __forceinline__ void conv2_lane(const float* pool,
                                           const float* __restrict__ w2,
                                           const float* __restrict__ b2,
                                           float yp[16]) {
  const int tid = threadIdx.x;
  const int imgl = tid >> 4, o = tid & 15;
  const float* pbase = pool + imgl * POOL_IST;

  float4 w2v[6];
#pragma unroll
  for (int c = 0; c < 6; ++c)
    w2v[c] = reinterpret_cast<const float4*>(w2)[o * 6 + c];
  const float yb = b2[o];
#pragma unroll
  for (int p = 0; p < 16; ++p) yp[p] = yb;

#pragma unroll
  for (int c = 0; c < 6; ++c) {
    const float* pcb = pbase + c * POOL_CST;
    const float w00 = w2v[c].x, w01 = w2v[c].y;
    const float w10 = w2v[c].z, w11 = w2v[c].w;
    float r[2][6];
    load6(pcb, r[0]);
#pragma unroll
    for (int i2 = 0; i2 < 4; ++i2) {
      float* top = r[i2 & 1];
      float* bot = r[(i2 + 1) & 1];
      load6(pcb + (i2 + 1) * 6, bot);
#pragma unroll
      for (int j2 = 0; j2 < 4; ++j2) {
        float acc = yp[i2 * 4 + j2];
        acc = fmaf(w00, top[j2], acc);
        acc = fmaf(w01, top[j2 + 1], acc);
        acc = fmaf(w10, bot[j2], acc);
        acc = fmaf(w11, bot[j2 + 1], acc);
        yp[i2 * 4 + j2] = acc;
      }
    }
  }
}

// ---------------- Kernel A: conv1 raw-output statistics ----------------
__global__ __launch_bounds__(256) void k_stats1(
    const float* __restrict__ x, const float* __restrict__ w1,
    const float* __restrict__ b1, float* ws) {
  __shared__ __align__(16) float xl[16 * PST];
  __shared__ float red[4][12];
  stage_x(x, xl, blockIdx.x);

  const int tid = threadIdx.x;
  const float* base = xl + (tid >> 4) * PST;
  float sum[6], sq[6];
#pragma unroll
  for (int c = 0; c < 6; ++c) { sum[c] = 0.f; sq[c] = 0.f; }

#pragma unroll 1
  for (int p = tid & 15; p < 100; p += 16) {
    const int i = p / 10, j = p % 10;
    const float* pb = base + i * 12 + j;
    float t0 = pb[0],  t1 = pb[1],  t2 = pb[2];
    float t3 = pb[12], t4 = pb[13], t5 = pb[14];
    float t6 = pb[24], t7 = pb[25], t8 = pb[26];
#pragma unroll
    for (int c = 0; c < 6; ++c) {
      float y = b1[c];
      y = fmaf(w1[c * 9 + 0], t0, y); y = fmaf(w1[c * 9 + 1], t1, y);
      y = fmaf(w1[c * 9 + 2], t2, y); y = fmaf(w1[c * 9 + 3], t3, y);
      y = fmaf(w1[c * 9 + 4], t4, y); y = fmaf(w1[c * 9 + 5], t5, y);
      y = fmaf(w1[c * 9 + 6], t6, y); y = fmaf(w1[c * 9 + 7], t7, y);
      y = fmaf(w1[c * 9 + 8], t8, y);
      sum[c] += y;
      sq[c] = fmaf(y, y, sq[c]);
    }
  }

  const int wid = tid >> 6, lane = tid & 63;
#pragma unroll
  for (int c = 0; c < 6; ++c) {
    const float s = wave_sum(sum[c]);
    const float q = wave_sum(sq[c]);
    if (lane == 0) { red[wid][c] = s; red[wid][6 + c] = q; }
  }
  __syncthreads();
  if (tid < 12) {
    const float tot = red[0][tid] + red[1][tid] + red[2][tid] + red[3][tid];
    atomicAdd(&ws[tid < 6 ? WS_SUM1 + tid : WS_SQ1 + tid - 6], tot);
  }
}

// -------- fold kernels: BN stats -> (sc, sh) and folded conv1 weights ------
__global__ void k_fold1(const float* __restrict__ g1,
                        const float* __restrict__ be1,
                        const float* __restrict__ w1,
                        const float* __restrict__ b1, float* ws, float inv_n) {
  const int c = threadIdx.x;
  if (c < 6) {
    const float mean = ws[WS_SUM1 + c] * inv_n;
    const float var  = ws[WS_SQ1 + c] * inv_n - mean * mean;
    const float sc   = g1[c] * rsqrtf(var + 1e-5f);
    ws[WS_SC1 + c] = sc;
    ws[WS_SH1 + c] = be1[c] - mean * sc;
  }
  __syncthreads();
  if (c < 54) ws[WS_W1S + c] = w1[c] * ws[WS_SC1 + c / 9];
  if (c < 6)  ws[WS_B1S + c] = fmaf(b1[c], ws[WS_SC1 + c], ws[WS_SH1 + c]);
}

__global__ void k_fold2(const float* __restrict__ g2,
                        const float* __restrict__ be2, float* ws, float inv_n) {
  const int c = threadIdx.x;
  if (c < 16) {
    const float mean = ws[WS_SUM2 + c] * inv_n;
    const float var  = ws[WS_SQ2 + c] * inv_n - mean * mean;
    const float sc   = g2[c] * rsqrtf(var + 1e-5f);
    ws[WS_SC2 + c] = sc;
    ws[WS_SH2 + c] = be2[c] - mean * sc;
  }
}

// ---------------- Kernel B: conv2 output statistics (+ pool store) --------
__global__ __launch_bounds__(256, 2) void k_stats2(
    const float* __restrict__ x, const float* __restrict__ w2,
    const float* __restrict__ b2, float* ws, float* __restrict__ g_pool,
    int store_pool) {
  __shared__ __align__(16) float xl[16 * PST];
  __shared__ __align__(16) float pool[16 * POOL_IST];
  __shared__ float red[4][32];
  stage_x(x, xl, blockIdx.x);

  pooled_front_coop(xl, pool, ws);
  __syncthreads();

  const int tid = threadIdx.x;
  if (store_pool) {  // stream pool to global (overlaps with conv2 below)
    float4* gp4 = reinterpret_cast<float4*>(g_pool) +
                  (size_t)blockIdx.x * (16 * POOL_IST / 4);
    const float4* pl4 = reinterpret_cast<const float4*>(pool);
#pragma unroll
    for (int k = 0; k < 4; ++k) {
      const int i = tid + k * 256;
      if (i < 16 * POOL_IST / 4) gp4[i] = pl4[i];
    }
  }

  float yp[16];
  conv2_lane(pool, w2, b2, yp);

  float s = 0.f, q = 0.f;
#pragma unroll
  for (int p = 0; p < 16; ++p) { s += yp[p]; q = fmaf(yp[p], yp[p], q); }
  s += __shfl_xor(s, 16, 64); s += __shfl_xor(s, 32, 64);
  q += __shfl_xor(q, 16, 64); q += __shfl_xor(q, 32, 64);

  const int wid = tid >> 6, lane = tid & 63;
  if (lane < 16) { red[wid][lane] = s; red[wid][16 + lane] = q; }
  __syncthreads();
  if (tid < 32) {
    const float tot = red[0][tid] + red[1][tid] + red[2][tid] + red[3][tid];
    atomicAdd(&ws[tid < 16 ? WS_SUM2 + tid : WS_SQ2 + tid - 16], tot);
  }
}

// -------- k_final tail: conv2 -> BN2+ReLU+pool -> FC1/FC2/FC3 -> out -------
__device__ __forceinline__ void final_tail(
    const float* pool, const float* __restrict__ w2,
    const float* __restrict__ b2, const float* __restrict__ fw1,
    const float* __restrict__ fb1, const float* __restrict__ fw2,
    const float* __restrict__ fb2, const float* __restrict__ fw3,
    const float* __restrict__ fb3, const float* ws, float* __restrict__ out,
    float* lds_h, float* lds_a1, float* lds_a2) {
  float yp[16];
  conv2_lane(pool, w2, b2, yp);

  const int tid = threadIdx.x;
  const int imgl = tid >> 4, o = tid & 15;

  const float sc2 = ws[WS_SC2 + o], sh2 = ws[WS_SH2 + o];
  float hq[4] = {0.f, 0.f, 0.f, 0.f};
#pragma unroll
  for (int i2 = 0; i2 < 4; ++i2)
#pragma unroll
    for (int j2 = 0; j2 < 4; ++j2)
      hq[(i2 >> 1) * 2 + (j2 >> 1)] +=
          fmaxf(fmaf(yp[i2 * 4 + j2], sc2, sh2), 0.f);
  float4 hv4;
  hv4.x = 0.25f * hq[0]; hv4.y = 0.25f * hq[1];
  hv4.z = 0.25f * hq[2]; hv4.w = 0.25f * hq[3];
  *reinterpret_cast<float4*>(lds_h + imgl * 68 + o * 4) = hv4;
  __syncthreads();

  const int al = o;
  const float* hrow = lds_h + imgl * 68;
  const bool has2 = (al + 16) < 30;
  float acc0 = fb1[al];
  float acc1 = has2 ? fb1[al + 16] : 0.f;
  const float4* fa = reinterpret_cast<const float4*>(fw1 + al * 64);
  const float4* fb = reinterpret_cast<const float4*>(fw1 + (has2 ? (al + 16) * 64 : 0));
#pragma unroll
  for (int kk = 0; kk < 16; ++kk) {
    const float4 hv = *reinterpret_cast<const float4*>(hrow + kk * 4);
    const float4 wa = fa[kk];
    const float4 wb = fb[kk];
    acc0 = fmaf(wa.x, hv.x, acc0); acc0 = fmaf(wa.y, hv.y, acc0);
    acc0 = fmaf(wa.z, hv.z, acc0); acc0 = fmaf(wa.w, hv.w, acc0);
    acc1 = fmaf(wb.x, hv.x, acc1); acc1 = fmaf(wb.y, hv.y, acc1);
    acc1 = fmaf(wb.z, hv.z, acc1); acc1 = fmaf(wb.w, hv.w, acc1);
  }
  lds_a1[imgl * 33 + al] = fmaxf(acc0, 0.f);
  if (has2) lds_a1[imgl * 33 + al + 16] = fmaxf(acc1, 0.f);
  __syncthreads();

  if (al < 15) {
    float acc = fb2[al];
#pragma unroll 1
    for (int j = 0; j < 30; ++j)
      acc = fmaf(fw2[al * 30 + j], lds_a1[imgl * 33 + j], acc);
    lds_a2[imgl * 17 + al] = fmaxf(acc, 0.f);
  }
  __syncthreads();

  if (al < 10) {
    float acc = fb3[al];
#pragma unroll 1
    for (int j = 0; j < 15; ++j)
      acc = fmaf(fw3[al * 15 + j], lds_a2[imgl * 17 + j], acc);
    out[(size_t)(blockIdx.x * 16 + imgl) * 10 + al] = acc;
  }
}

// ---------------- Kernel C (pool path): stage pool from global ------------
__global__ __launch_bounds__(256, 2) void k_final_pool(
    const float* __restrict__ g_pool, const float* __restrict__ w2,
    const float* __restrict__ b2, const float* __restrict__ fw1,
    const float* __restrict__ fb1, const float* __restrict__ fw2,
    const float* __restrict__ fb2, const float* __restrict__ fw3,
    const float* __restrict__ fb3, float* ws, float* __restrict__ out) {
  __shared__ __align__(16) float pool[16 * POOL_IST];
  __shared__ __align__(16) float lds_h[16 * 68];
  __shared__ float lds_a1[16 * 33];
  __shared__ float lds_a2[16 * 17];

  const int tid = threadIdx.x;
  const float4* gp4 = reinterpret_cast<const float4*>(g_pool) +
                      (size_t)blockIdx.x * (16 * POOL_IST / 4);
  float4* pl4 = reinterpret_cast<float4*>(pool);
#pragma unroll
  for (int k = 0; k < 4; ++k) {
    const int i = tid + k * 256;
    if (i < 16 * POOL_IST / 4) pl4[i] = gp4[i];
  }
  __syncthreads();

  final_tail(pool, w2, b2, fw1, fb1, fw2, fb2, fw3, fb3, ws, out,
             lds_h, lds_a1, lds_a2);
}

// ---------------- Kernel C (recompute path): front in-kernel --------------
__global__ __launch_bounds__(256, 2) void k_final_rc(
    const float* __restrict__ x, const float* __restrict__ w2,
    const float* __restrict__ b2, const float* __restrict__ fw1,
    const float* __restrict__ fb1, const float* __restrict__ fw2,
    const float* __restrict__ fb2, const float* __restrict__ fw3,
    const float* __restrict__ fb3, float* ws, float* __restrict__ out) {
  __shared__ __align__(16) float xl[16 * PST];
  __shared__ __align__(16) float pool[16 * POOL_IST];
  __shared__ __align__(16) float lds_h[16 * 68];
  __shared__ float lds_a1[16 * 33];
  __shared__ float lds_a2[16 * 17];

  stage_x(x, xl, blockIdx.x);
  pooled_front_coop(xl, pool, ws);
  __syncthreads();

  final_tail(pool, w2, b2, fw1, fb1, fw2, fb2, fw3, fb3, ws, out,
             lds_h, lds_a1, lds_a2);
}

extern "C" void kernel_launch(void* const* d_in, const int* in_sizes, int n_in,
                              void* d_out, int out_size, void* d_ws, size_t ws_size,
                              hipStream_t stream) {
  (void)n_in; (void)out_size;
  const float* x   = (const float*)d_in[0];
  const float* w1  = (const float*)d_in[1];
  const float* b1  = (const float*)d_in[2];
  const float* g1  = (const float*)d_in[3];
  const float* be1 = (const float*)d_in[4];
  const float* w2  = (const float*)d_in[5];
  const float* b2  = (const float*)d_in[6];
  const float* g2  = (const float*)d_in[7];
  const float* be2 = (const float*)d_in[8];
  const float* fw1 = (const float*)d_in[9];
  const float* fb1 = (const float*)d_in[10];
  const float* fw2 = (const float*)d_in[11];
  const float* fb2 = (const float*)d_in[12];
  const float* fw3 = (const float*)d_in[13];
  const float* fb3 = (const float*)d_in[14];
  float* out = (float*)d_out;
  float* ws  = (float*)d_ws;

  const int Btot = in_sizes[0] / 64;  // 131072; % 16 == 0
  const float inv_n1 = 1.0f / ((float)Btot * 100.0f);
  const float inv_n2 = 1.0f / ((float)Btot * 16.0f);
  const int grid = Btot / 16;

  float* g_pool = ws + WS_POOL_START;
  const size_t need_bytes =
      ((size_t)WS_POOL_START + (size_t)Btot * POOL_IST) * sizeof(float);
  const int use_pool = (ws_size >= need_bytes) ? 1 : 0;

  hipMemsetAsync(ws, 0, WS_NFLOATS * sizeof(float), stream);

  k_stats1<<<grid, 256, 0, stream>>>(x, w1, b1, ws);
  k_fold1<<<1, 64, 0, stream>>>(g1, be1, w1, b1, ws, inv_n1);
  k_stats2<<<grid, 256, 0, stream>>>(x, w2, b2, ws, g_pool, use_pool);
  k_fold2<<<1, 64, 0, stream>>>(g2, be2, ws, inv_n2);
  if (use_pool) {
    k_final_pool<<<grid, 256, 0, stream>>>(g_pool, w2, b2, fw1, fb1, fw2, fb2,
                                           fw3, fb3, ws, out);
  } else {
    k_final_rc<<<grid, 256, 0, stream>>>(x, w2, b2, fw1, fb1, fw2, fb2,
                                         fw3, fb3, ws, out);
  }
}

// Round 9
// 333.744 us; speedup vs baseline: 2.1965x; 1.4117x over previous
//
#include <hip/hip_runtime.h>

// ws float layout:
//  [0:16)   sum2    [16:32) sumsq2
//  [32:48)  sc2     [48:64) sh2
//  [64:118) w1s (w1*sc1)    [118:124) b1s
//  [124]    T (sum of all x)
//  [125:138) A[13] autocorrelations
//  scratch (y or pool) starts at float 160
#define WS_SUM2 0
#define WS_SQ2  16
#define WS_SC2  32
#define WS_SH2  48
#define WS_W1S  64
#define WS_B1S  118
#define WS_T    124
#define WS_A    125
#define WS_NFLOATS 138
#define WS_SCRATCH 160

#define PST 146        // per-image LDS stride: 12x12 padded image + 2 (even)
#define POOL_CST 36    // per-channel pooled stride (5x5 map, row stride 6)
#define POOL_IST 220   // per-image pooled stride

__device__ __forceinline__ float wave_sum(float v) {
#pragma unroll
  for (int off = 32; off > 0; off >>= 1) v += __shfl_down(v, off, 64);
  return v;
}

// Write 16 zero-padded images' interiors (assumes pad already zeroed).
__device__ __forceinline__ void stage_x_interior(const float* __restrict__ x,
                                                 float* xl, int blk) {
  const int tid = threadIdx.x;
  const float4 v = reinterpret_cast<const float4*>(x)[blk * 256 + tid];
  const int imgl = tid >> 4;
  const int f = (tid & 15) * 4;
  const int row = f >> 3, col = f & 7;
  float* dst = xl + imgl * PST + (row + 2) * 12 + (col + 2);
  dst[0] = v.x; dst[1] = v.y; dst[2] = v.z; dst[3] = v.w;
}

__device__ __forceinline__ void stage_x(const float* __restrict__ x,
                                        float* xl, int blk) {
  const int tid = threadIdx.x;
  for (int i = tid; i < 16 * PST; i += 256) xl[i] = 0.f;
  __syncthreads();
  stage_x_interior(x, xl, blk);
  __syncthreads();
}

// Cooperative front: conv1 (BN1 folded into w1s/b1s) + ReLU + meanpool2
// -> pool[6][5x5 (stride 6)] per image in LDS; each value computed once.
__device__ __forceinline__ void pooled_front_coop(const float* xl, float* pool,
                                                  const float* wsf) {
  const int tid = threadIdx.x;
  const int imgl = tid >> 4, l16 = tid & 15;
  const float* ibase = xl + imgl * PST;
  float* pbase = pool + imgl * POOL_IST;

#pragma unroll
  for (int k2 = 0; k2 < 2; ++k2) {
    const int p = l16 + 16 * k2;
    if (p < 25) {
      const int r = p / 5, s = p % 5;
      const float* wb = ibase + (2 * r) * 12 + 2 * s;
      float X[16];
#pragma unroll
      for (int a = 0; a < 4; ++a) {
        const float2* wr = reinterpret_cast<const float2*>(wb + a * 12);
        const float2 e0 = wr[0], e1 = wr[1];
        X[a * 4 + 0] = e0.x; X[a * 4 + 1] = e0.y;
        X[a * 4 + 2] = e1.x; X[a * 4 + 3] = e1.y;
      }
#pragma unroll
      for (int i = 0; i < 16; ++i) asm volatile("" : "+v"(X[i]));
#pragma unroll
      for (int c = 0; c < 6; ++c) {
        const float bc = wsf[WS_B1S + c];
        float acc = 0.f;
#pragma unroll
        for (int di = 0; di < 2; ++di) {
#pragma unroll
          for (int dj = 0; dj < 2; ++dj) {
            float z = bc;
#pragma unroll
            for (int u = 0; u < 3; ++u)
#pragma unroll
              for (int v = 0; v < 3; ++v)
                z = fmaf(wsf[WS_W1S + c * 9 + u * 3 + v],
                         X[(di + u) * 4 + dj + v], z);
            acc += fmaxf(z, 0.f);
          }
        }
        pbase[c * POOL_CST + r * 6 + s] = 0.25f * acc;
      }
    }
  }
}

__device__ __forceinline__ void load6(const float* p, float r[6]) {
  const float2* q = reinterpret_cast<const float2*>(p);
  const float2 a = q[0], b = q[1], c = q[2];
  r[0] = a.x; r[1] = a.y; r[2] = b.x; r[3] = b.y; r[4] = c.x; r[5] = c.y;
}

// Channel-per-lane conv2, rolling 2-row stencil (each pooled value read once).
__device__ __forceinline__ void conv2_lane(const float* pool,
                                           const float* __restrict__ w2,
                                           const float* __restrict__ b2,
                                           float yp[16]) {
  const int tid = threadIdx.x;
  const int imgl = tid >> 4, o = tid & 15;
  const float* pbase = pool + imgl * POOL_IST;

  float4 w2v[6];
#pragma unroll
  for (int c = 0; c < 6; ++c)
    w2v[c] = reinterpret_cast<const float4*>(w2)[o * 6 + c];
  const float yb = b2[o];
#pragma unroll
  for (int p = 0; p < 16; ++p) yp[p] = yb;

#pragma unroll
  for (int c = 0; c < 6; ++c) {
    const float* pcb = pbase + c * POOL_CST;
    const float w00 = w2v[c].x, w01 = w2v[c].y;
    const float w10 = w2v[c].z, w11 = w2v[c].w;
    float r[2][6];
    load6(pcb, r[0]);
#pragma unroll
    for (int i2 = 0; i2 < 4; ++i2) {
      float* top = r[i2 & 1];
      float* bot = r[(i2 + 1) & 1];
      load6(pcb + (i2 + 1) * 6, bot);
#pragma unroll
      for (int j2 = 0; j2 < 4; ++j2) {
        float acc = yp[i2 * 4 + j2];
        acc = fmaf(w00, top[j2], acc);
        acc = fmaf(w01, top[j2 + 1], acc);
        acc = fmaf(w10, bot[j2], acc);
        acc = fmaf(w11, bot[j2 + 1], acc);
        yp[i2 * 4 + j2] = acc;
      }
    }
  }
}

// ------- Kernel A: x total-sum + 13 autocorrelations (grid-strided) -------
// sum1/sumsq1 of conv1 output follow in closed form (pad-2 windows cover the
// full 8x8 image for every tap) -> computed in k_fold1.
__global__ __launch_bounds__(256) void k_stats1(
    const float* __restrict__ x, float* ws, int nblk) {
  __shared__ __align__(16) float xl[16 * PST];
  __shared__ float red[4][16];
  const int tid = threadIdx.x;
  for (int i = tid; i < 16 * PST; i += 256) xl[i] = 0.f;

  float T = 0.f, A[13];
#pragma unroll
  for (int i = 0; i < 13; ++i) A[i] = 0.f;

  for (int blk = blockIdx.x; blk < nblk; blk += gridDim.x) {
    __syncthreads();  // pad-zero / prev-iter readers done
    stage_x_interior(x, xl, blk);
    __syncthreads();
    const float* ib = xl + (tid >> 4) * PST;
    const int l16 = tid & 15;
#pragma unroll
    for (int k = 0; k < 4; ++k) {
      const int p = l16 + k * 16;           // pixel 0..63
      const int r = p >> 3, c = p & 7;
      const float* q = ib + (r + 2) * 12 + (c + 2);
      const float xc = q[0];
      T += xc;
      // lags: (0,0),(0,1),(0,2),(1,-2..2),(2,-2..2)
      A[0]  = fmaf(xc, q[0],  A[0]);
      A[1]  = fmaf(xc, q[1],  A[1]);
      A[2]  = fmaf(xc, q[2],  A[2]);
      A[3]  = fmaf(xc, q[10], A[3]);
      A[4]  = fmaf(xc, q[11], A[4]);
      A[5]  = fmaf(xc, q[12], A[5]);
      A[6]  = fmaf(xc, q[13], A[6]);
      A[7]  = fmaf(xc, q[14], A[7]);
      A[8]  = fmaf(xc, q[22], A[8]);
      A[9]  = fmaf(xc, q[23], A[9]);
      A[10] = fmaf(xc, q[24], A[10]);
      A[11] = fmaf(xc, q[25], A[11]);
      A[12] = fmaf(xc, q[26], A[12]);
    }
  }

  const int wid = tid >> 6, lane = tid & 63;
#pragma unroll
  for (int i = 0; i < 14; ++i) {
    const float v = wave_sum(i == 0 ? T : A[i - 1]);
    if (lane == 0) red[wid][i] = v;
  }
  __syncthreads();
  if (tid < 14) {
    const float tot = red[0][tid] + red[1][tid] + red[2][tid] + red[3][tid];
    atomicAdd(&ws[WS_T + tid], tot);
  }
}

// -------- fold1: closed-form BN1 stats -> folded conv1 weights ------------
__global__ void k_fold1(const float* __restrict__ g1,
                        const float* __restrict__ be1,
                        const float* __restrict__ w1,
                        const float* __restrict__ b1, float* ws, float NP) {
  const int c = threadIdx.x;
  if (c >= 6) return;
  float Av[13];
#pragma unroll
  for (int i = 0; i < 13; ++i) Av[i] = ws[WS_A + i];
  const float T = ws[WS_T];
  float w[9];
#pragma unroll
  for (int k = 0; k < 9; ++k) w[k] = w1[c * 9 + k];
  float sw = 0.f;
#pragma unroll
  for (int k = 0; k < 9; ++k) sw += w[k];
  float q2 = 0.f;
#pragma unroll
  for (int k1 = 0; k1 < 9; ++k1) {
    const int u1 = k1 / 3, v1 = k1 % 3;
#pragma unroll
    for (int k2 = 0; k2 < 9; ++k2) {
      int du = k2 / 3 - u1, dv = k2 % 3 - v1;
      if (du < 0 || (du == 0 && dv < 0)) { du = -du; dv = -dv; }
      const float a = (du == 0) ? Av[dv] : Av[3 + (du - 1) * 5 + dv + 2];
      q2 = fmaf(w[k1] * w[k2], a, q2);
    }
  }
  const float b = b1[c];
  const float sum1 = sw * T + NP * b;
  const float sumsq1 = q2 + 2.f * b * sw * T + NP * b * b;
  const float mean = sum1 / NP;
  const float var = sumsq1 / NP - mean * mean;
  const float sc = g1[c] * rsqrtf(var + 1e-5f);
  const float sh = be1[c] - mean * sc;
#pragma unroll
  for (int k = 0; k < 9; ++k) ws[WS_W1S + c * 9 + k] = w[k] * sc;
  ws[WS_B1S + c] = fmaf(b, sc, sh);
}

__global__ void k_fold2(const float* __restrict__ g2,
                        const float* __restrict__ be2, float* ws, float inv_n) {
  const int c = threadIdx.x;
  if (c < 16) {
    const float mean = ws[WS_SUM2 + c] * inv_n;
    const float var  = ws[WS_SQ2 + c] * inv_n - mean * mean;
    const float sc   = g2[c] * rsqrtf(var + 1e-5f);
    ws[WS_SC2 + c] = sc;
    ws[WS_SH2 + c] = be2[c] - mean * sc;
  }
}

// ------- Kernel B: conv2 output statistics (+ y or pool scratch store) ----
// mode: 0 = none, 1 = store pool, 2 = store raw conv2 y
__global__ __launch_bounds__(256, 2) void k_stats2(
    const float* __restrict__ x, const float* __restrict__ w2,
    const float* __restrict__ b2, float* ws, float* __restrict__ g_scr,
    int mode) {
  __shared__ __align__(16) float xl[16 * PST];
  __shared__ __align__(16) float pool[16 * POOL_IST];
  __shared__ float red[4][32];
  stage_x(x, xl, blockIdx.x);

  pooled_front_coop(xl, pool, ws);
  __syncthreads();

  const int tid = threadIdx.x;
  if (mode == 1) {
    float4* gp4 = reinterpret_cast<float4*>(g_scr) +
                  (size_t)blockIdx.x * (16 * POOL_IST / 4);
    const float4* pl4 = reinterpret_cast<const float4*>(pool);
#pragma unroll
    for (int k = 0; k < 4; ++k) {
      const int i = tid + k * 256;
      if (i < 16 * POOL_IST / 4) gp4[i] = pl4[i];
    }
  }

  float yp[16];
  conv2_lane(pool, w2, b2, yp);

  const int imgl = tid >> 4, o = tid & 15;
  if (mode == 2) {  // y layout: [img][i2][o][j2] (fully coalesced both ways)
    float* gy = g_scr + ((size_t)(blockIdx.x * 16 + imgl)) * 256 + o * 4;
#pragma unroll
    for (int i2 = 0; i2 < 4; ++i2) {
      float4 t;
      t.x = yp[i2 * 4 + 0]; t.y = yp[i2 * 4 + 1];
      t.z = yp[i2 * 4 + 2]; t.w = yp[i2 * 4 + 3];
      *reinterpret_cast<float4*>(gy + i2 * 64) = t;
    }
  }

  float s = 0.f, q = 0.f;
#pragma unroll
  for (int p = 0; p < 16; ++p) { s += yp[p]; q = fmaf(yp[p], yp[p], q); }
  s += __shfl_xor(s, 16, 64); s += __shfl_xor(s, 32, 64);
  q += __shfl_xor(q, 16, 64); q += __shfl_xor(q, 32, 64);

  const int wid = tid >> 6, lane = tid & 63;
  if (lane < 16) { red[wid][lane] = s; red[wid][16 + lane] = q; }
  __syncthreads();
  if (tid < 32) {
    const float tot = red[0][tid] + red[1][tid] + red[2][tid] + red[3][tid];
    atomicAdd(&ws[tid < 16 ? WS_SUM2 + tid : WS_SQ2 + tid - 16], tot);
  }
}

// -------- shared FC tail (from lds_h) -------------------------------------
__device__ __forceinline__ void fc_tail(
    const float* __restrict__ fw1, const float* __restrict__ fb1,
    const float* __restrict__ fw2, const float* __restrict__ fb2,
    const float* __restrict__ fw3, const float* __restrict__ fb3,
    float* __restrict__ out, int blk, float* lds_h, float* lds_a1,
    float* lds_a2) {
  const int tid = threadIdx.x;
  const int imgl = tid >> 4, al = tid & 15;
  const float* hrow = lds_h + imgl * 68;
  const bool has2 = (al + 16) < 30;
  float acc0 = fb1[al];
  float acc1 = has2 ? fb1[al + 16] : 0.f;
  const float4* fa = reinterpret_cast<const float4*>(fw1 + al * 64);
  const float4* fb = reinterpret_cast<const float4*>(fw1 + (has2 ? (al + 16) * 64 : 0));
#pragma unroll
  for (int kk = 0; kk < 16; ++kk) {
    const float4 hv = *reinterpret_cast<const float4*>(hrow + kk * 4);
    const float4 wa = fa[kk];
    const float4 wb = fb[kk];
    acc0 = fmaf(wa.x, hv.x, acc0); acc0 = fmaf(wa.y, hv.y, acc0);
    acc0 = fmaf(wa.z, hv.z, acc0); acc0 = fmaf(wa.w, hv.w, acc0);
    acc1 = fmaf(wb.x, hv.x, acc1); acc1 = fmaf(wb.y, hv.y, acc1);
    acc1 = fmaf(wb.z, hv.z, acc1); acc1 = fmaf(wb.w, hv.w, acc1);
  }
  lds_a1[imgl * 33 + al] = fmaxf(acc0, 0.f);
  if (has2) lds_a1[imgl * 33 + al + 16] = fmaxf(acc1, 0.f);
  __syncthreads();

  if (al < 15) {
    float acc = fb2[al];
#pragma unroll 1
    for (int j = 0; j < 30; ++j)
      acc = fmaf(fw2[al * 30 + j], lds_a1[imgl * 33 + j], acc);
    lds_a2[imgl * 17 + al] = fmaxf(acc, 0.f);
  }
  __syncthreads();

  if (al < 10) {
    float acc = fb3[al];
#pragma unroll 1
    for (int j = 0; j < 15; ++j)
      acc = fmaf(fw3[al * 15 + j], lds_a2[imgl * 17 + j], acc);
    out[(size_t)(blk * 16 + imgl) * 10 + al] = acc;
  }
}

__device__ __forceinline__ void bn2_pool_store_h(const float yp[16],
                                                 const float* ws,
                                                 float* lds_h) {
  const int tid = threadIdx.x;
  const int imgl = tid >> 4, o = tid & 15;
  const float sc2 = ws[WS_SC2 + o], sh2 = ws[WS_SH2 + o];
  float hq[4] = {0.f, 0.f, 0.f, 0.f};
#pragma unroll
  for (int i2 = 0; i2 < 4; ++i2)
#pragma unroll
    for (int j2 = 0; j2 < 4; ++j2)
      hq[(i2 >> 1) * 2 + (j2 >> 1)] +=
          fmaxf(fmaf(yp[i2 * 4 + j2], sc2, sh2), 0.f);
  float4 hv4;
  hv4.x = 0.25f * hq[0]; hv4.y = 0.25f * hq[1];
  hv4.z = 0.25f * hq[2]; hv4.w = 0.25f * hq[3];
  *reinterpret_cast<float4*>(lds_h + imgl * 68 + o * 4) = hv4;
}

// ---------------- Kernel C (y path): conv-free ----------------------------
__global__ __launch_bounds__(256) void k_final_y(
    const float* __restrict__ g_y, const float* __restrict__ fw1,
    const float* __restrict__ fb1, const float* __restrict__ fw2,
    const float* __restrict__ fb2, const float* __restrict__ fw3,
    const float* __restrict__ fb3, float* ws, float* __restrict__ out) {
  __shared__ __align__(16) float lds_h[16 * 68];
  __shared__ float lds_a1[16 * 33];
  __shared__ float lds_a2[16 * 17];

  const int tid = threadIdx.x;
  const int imgl = tid >> 4, o = tid & 15;
  const float* gy = g_y + ((size_t)(blockIdx.x * 16 + imgl)) * 256 + o * 4;
  float yp[16];
#pragma unroll
  for (int i2 = 0; i2 < 4; ++i2) {
    const float4 v = *reinterpret_cast<const float4*>(gy + i2 * 64);
    yp[i2 * 4 + 0] = v.x; yp[i2 * 4 + 1] = v.y;
    yp[i2 * 4 + 2] = v.z; yp[i2 * 4 + 3] = v.w;
  }
  bn2_pool_store_h(yp, ws, lds_h);
  __syncthreads();
  fc_tail(fw1, fb1, fw2, fb2, fw3, fb3, out, blockIdx.x, lds_h, lds_a1, lds_a2);
}

// ---------------- Kernel C (pool path) ------------------------------------
__global__ __launch_bounds__(256, 2) void k_final_pool(
    const float* __restrict__ g_pool, const float* __restrict__ w2,
    const float* __restrict__ b2, const float* __restrict__ fw1,
    const float* __restrict__ fb1, const float* __restrict__ fw2,
    const float* __restrict__ fb2, const float* __restrict__ fw3,
    const float* __restrict__ fb3, float* ws, float* __restrict__ out) {
  __shared__ __align__(16) float pool[16 * POOL_IST];
  __shared__ __align__(16) float lds_h[16 * 68];
  __shared__ float lds_a1[16 * 33];
  __shared__ float lds_a2[16 * 17];

  const int tid = threadIdx.x;
  const float4* gp4 = reinterpret_cast<const float4*>(g_pool) +
                      (size_t)blockIdx.x * (16 * POOL_IST / 4);
  float4* pl4 = reinterpret_cast<float4*>(pool);
#pragma unroll
  for (int k = 0; k < 4; ++k) {
    const int i = tid + k * 256;
    if (i < 16 * POOL_IST / 4) pl4[i] = gp4[i];
  }
  __syncthreads();

  float yp[16];
  conv2_lane(pool, w2, b2, yp);
  bn2_pool_store_h(yp, ws, lds_h);
  __syncthreads();
  fc_tail(fw1, fb1, fw2, fb2, fw3, fb3, out, blockIdx.x, lds_h, lds_a1, lds_a2);
}

// ---------------- Kernel C (recompute path) -------------------------------
__global__ __launch_bounds__(256, 2) void k_final_rc(
    const float* __restrict__ x, const float* __restrict__ w2,
    const float* __restrict__ b2, const float* __restrict__ fw1,
    const float* __restrict__ fb1, const float* __restrict__ fw2,
    const float* __restrict__ fb2, const float* __restrict__ fw3,
    const float* __restrict__ fb3, float* ws, float* __restrict__ out) {
  __shared__ __align__(16) float xl[16 * PST];
  __shared__ __align__(16) float pool[16 * POOL_IST];
  __shared__ __align__(16) float lds_h[16 * 68];
  __shared__ float lds_a1[16 * 33];
  __shared__ float lds_a2[16 * 17];

  stage_x(x, xl, blockIdx.x);
  pooled_front_coop(xl, pool, ws);
  __syncthreads();

  float yp[16];
  conv2_lane(pool, w2, b2, yp);
  bn2_pool_store_h(yp, ws, lds_h);
  __syncthreads();
  fc_tail(fw1, fb1, fw2, fb2, fw3, fb3, out, blockIdx.x, lds_h, lds_a1, lds_a2);
}

extern "C" void kernel_launch(void* const* d_in, const int* in_sizes, int n_in,
                              void* d_out, int out_size, void* d_ws, size_t ws_size,
                              hipStream_t stream) {
  (void)n_in; (void)out_size;
  const float* x   = (const float*)d_in[0];
  const float* w1  = (const float*)d_in[1];
  const float* b1  = (const float*)d_in[2];
  const float* g1  = (const float*)d_in[3];
  const float* be1 = (const float*)d_in[4];
  const float* w2  = (const float*)d_in[5];
  const float* b2  = (const float*)d_in[6];
  const float* g2  = (const float*)d_in[7];
  const float* be2 = (const float*)d_in[8];
  const float* fw1 = (const float*)d_in[9];
  const float* fb1 = (const float*)d_in[10];
  const float* fw2 = (const float*)d_in[11];
  const float* fb2 = (const float*)d_in[12];
  const float* fw3 = (const float*)d_in[13];
  const float* fb3 = (const float*)d_in[14];
  float* out = (float*)d_out;
  float* ws  = (float*)d_ws;

  const int Btot = in_sizes[0] / 64;  // 131072; % 16 == 0
  const int nblk = Btot / 16;         // 8192
  const float NP1 = (float)Btot * 100.0f;
  const float inv_n2 = 1.0f / ((float)Btot * 16.0f);

  float* g_scr = ws + WS_SCRATCH;
  const size_t need_y    = ((size_t)WS_SCRATCH + (size_t)Btot * 256) * 4;
  const size_t need_pool = ((size_t)WS_SCRATCH + (size_t)Btot * (POOL_IST / 16)) * 4 * 16;
  const int mode = (ws_size >= need_y) ? 2 : (ws_size >= need_pool ? 1 : 0);

  hipMemsetAsync(ws, 0, WS_NFLOATS * sizeof(float), stream);

  k_stats1<<<1024, 256, 0, stream>>>(x, ws, nblk);
  k_fold1<<<1, 64, 0, stream>>>(g1, be1, w1, b1, ws, NP1);
  k_stats2<<<nblk, 256, 0, stream>>>(x, w2, b2, ws, g_scr, mode);
  k_fold2<<<1, 64, 0, stream>>>(g2, be2, ws, inv_n2);
  if (mode == 2) {
    k_final_y<<<nblk, 256, 0, stream>>>(g_scr, fw1, fb1, fw2, fb2, fw3, fb3,
                                        ws, out);
  } else if (mode == 1) {
    k_final_pool<<<nblk, 256, 0, stream>>>(g_scr, w2, b2, fw1, fb1, fw2, fb2,
                                           fw3, fb3, ws, out);
  } else {
    k_final_rc<<<nblk, 256, 0, stream>>>(x, w2, b2, fw1, fb1, fw2, fb2,
                                         fw3, fb3, ws, out);
  }
}

// Round 10
// 312.245 us; speedup vs baseline: 2.3477x; 1.0689x over previous
//
#include <hip/hip_runtime.h>

// ws float layout:
//  [0:16)    sum2      [16:32)  sumsq2
//  [64:118)  w1s (w1*sc1)   [118:124) b1s
//  [124]     T (sum of all x)
//  [125:138) A[13] autocorrelations
//  [144:528) w2s (w2*sc2)   [528:544) b2s (b2*sc2+sh2)
//  scratch (compact pool) starts at float 576
#define WS_SUM2 0
#define WS_SQ2  16
#define WS_W1S  64
#define WS_B1S  118
#define WS_T    124
#define WS_A    125
#define WS_W2S  144
#define WS_B2S  528
#define WS_ZERO_N 144
#define WS_SCRATCH 576

#define PST 146        // per-image LDS stride: 12x12 padded image + 2
#define POOL_CST 36    // per-channel pooled stride in stats2 LDS (rows of 6)
#define POOL_IST 220   // per-image pooled stride in stats2 LDS

#define GP_CST 30      // compact pool: per-channel 5 rows x stride 6
#define GP_IST 180     // compact pool: per-image floats
#define TILE_F (16 * GP_IST)  // 2880 floats per 16-image tile
#define TILES 4        // image-tiles per k_final block

__device__ __forceinline__ float wave_sum(float v) {
#pragma unroll
  for (int off = 32; off > 0; off >>= 1) v += __shfl_down(v, off, 64);
  return v;
}

// Write 16 zero-padded images' interiors (assumes pad already zeroed).
__device__ __forceinline__ void stage_x_interior(const float* __restrict__ x,
                                                 float* xl, int blk) {
  const int tid = threadIdx.x;
  const float4 v = reinterpret_cast<const float4*>(x)[blk * 256 + tid];
  const int imgl = tid >> 4;
  const int f = (tid & 15) * 4;
  const int row = f >> 3, col = f & 7;
  float* dst = xl + imgl * PST + (row + 2) * 12 + (col + 2);
  dst[0] = v.x; dst[1] = v.y; dst[2] = v.z; dst[3] = v.w;
}

__device__ __forceinline__ void stage_x(const float* __restrict__ x,
                                        float* xl, int blk) {
  const int tid = threadIdx.x;
  for (int i = tid; i < 16 * PST; i += 256) xl[i] = 0.f;
  __syncthreads();
  stage_x_interior(x, xl, blk);
  __syncthreads();
}

// Cooperative front: conv1 (BN1 folded into w1s/b1s) + ReLU + meanpool2
// -> pool[6][5x5 (row stride 6)] per image in LDS; each value computed once.
__device__ __forceinline__ void pooled_front_coop(const float* xl, float* pool,
                                                  const float* wsf) {
  const int tid = threadIdx.x;
  const int imgl = tid >> 4, l16 = tid & 15;
  const float* ibase = xl + imgl * PST;
  float* pbase = pool + imgl * POOL_IST;

#pragma unroll
  for (int k2 = 0; k2 < 2; ++k2) {
    const int p = l16 + 16 * k2;
    if (p < 25) {
      const int r = p / 5, s = p % 5;
      const float* wb = ibase + (2 * r) * 12 + 2 * s;
      float X[16];
#pragma unroll
      for (int a = 0; a < 4; ++a) {
        const float2* wr = reinterpret_cast<const float2*>(wb + a * 12);
        const float2 e0 = wr[0], e1 = wr[1];
        X[a * 4 + 0] = e0.x; X[a * 4 + 1] = e0.y;
        X[a * 4 + 2] = e1.x; X[a * 4 + 3] = e1.y;
      }
#pragma unroll
      for (int i = 0; i < 16; ++i) asm volatile("" : "+v"(X[i]));
#pragma unroll
      for (int c = 0; c < 6; ++c) {
        const float bc = wsf[WS_B1S + c];
        float acc = 0.f;
#pragma unroll
        for (int di = 0; di < 2; ++di) {
#pragma unroll
          for (int dj = 0; dj < 2; ++dj) {
            float z = bc;
#pragma unroll
            for (int u = 0; u < 3; ++u)
#pragma unroll
              for (int v = 0; v < 3; ++v)
                z = fmaf(wsf[WS_W1S + c * 9 + u * 3 + v],
                         X[(di + u) * 4 + dj + v], z);
            acc += fmaxf(z, 0.f);
          }
        }
        pbase[c * POOL_CST + r * 6 + s] = 0.25f * acc;
      }
    }
  }
}

__device__ __forceinline__ void load6(const float* p, float r[6]) {
  const float2* q = reinterpret_cast<const float2*>(p);
  const float2 a = q[0], b = q[1], c = q[2];
  r[0] = a.x; r[1] = a.y; r[2] = b.x; r[3] = b.y; r[4] = c.x; r[5] = c.y;
}

// Channel-per-lane conv2, rolling 2-row stencil (each pooled value read once).
// wgt: 24 floats per o (float4-aligned); bias: 16 floats.
template <int CST, int IST>
__device__ __forceinline__ void conv2_lane_t(const float* pool,
                                             const float* wgt,
                                             const float* bias,
                                             float yp[16]) {
  const int tid = threadIdx.x;
  const int imgl = tid >> 4, o = tid & 15;
  const float* pbase = pool + imgl * IST;

  float4 w2v[6];
#pragma unroll
  for (int c = 0; c < 6; ++c)
    w2v[c] = reinterpret_cast<const float4*>(wgt)[o * 6 + c];
  const float yb = bias[o];
#pragma unroll
  for (int p = 0; p < 16; ++p) yp[p] = yb;

#pragma unroll
  for (int c = 0; c < 6; ++c) {
    const float* pcb = pbase + c * CST;
    const float w00 = w2v[c].x, w01 = w2v[c].y;
    const float w10 = w2v[c].z, w11 = w2v[c].w;
    float r[2][6];
    load6(pcb, r[0]);
#pragma unroll
    for (int i2 = 0; i2 < 4; ++i2) {
      float* top = r[i2 & 1];
      float* bot = r[(i2 + 1) & 1];
      load6(pcb + (i2 + 1) * 6, bot);
#pragma unroll
      for (int j2 = 0; j2 < 4; ++j2) {
        float acc = yp[i2 * 4 + j2];
        acc = fmaf(w00, top[j2], acc);
        acc = fmaf(w01, top[j2 + 1], acc);
        acc = fmaf(w10, bot[j2], acc);
        acc = fmaf(w11, bot[j2 + 1], acc);
        yp[i2 * 4 + j2] = acc;
      }
    }
  }
}

// ------- Kernel A: x total-sum + 13 autocorrelations (grid-strided) -------
__global__ __launch_bounds__(256) void k_stats1(
    const float* __restrict__ x, float* ws, int nblk) {
  __shared__ __align__(16) float xl[16 * PST];
  __shared__ float red[4][16];
  const int tid = threadIdx.x;
  for (int i = tid; i < 16 * PST; i += 256) xl[i] = 0.f;

  float T = 0.f, A[13];
#pragma unroll
  for (int i = 0; i < 13; ++i) A[i] = 0.f;

  for (int blk = blockIdx.x; blk < nblk; blk += gridDim.x) {
    __syncthreads();
    stage_x_interior(x, xl, blk);
    __syncthreads();
    const float* ib = xl + (tid >> 4) * PST;
    const int l16 = tid & 15;
#pragma unroll
    for (int k = 0; k < 4; ++k) {
      const int p = l16 + k * 16;
      const int r = p >> 3, c = p & 7;
      const float* q = ib + (r + 2) * 12 + (c + 2);
      const float xc = q[0];
      T += xc;
      A[0]  = fmaf(xc, q[0],  A[0]);
      A[1]  = fmaf(xc, q[1],  A[1]);
      A[2]  = fmaf(xc, q[2],  A[2]);
      A[3]  = fmaf(xc, q[10], A[3]);
      A[4]  = fmaf(xc, q[11], A[4]);
      A[5]  = fmaf(xc, q[12], A[5]);
      A[6]  = fmaf(xc, q[13], A[6]);
      A[7]  = fmaf(xc, q[14], A[7]);
      A[8]  = fmaf(xc, q[22], A[8]);
      A[9]  = fmaf(xc, q[23], A[9]);
      A[10] = fmaf(xc, q[24], A[10]);
      A[11] = fmaf(xc, q[25], A[11]);
      A[12] = fmaf(xc, q[26], A[12]);
    }
  }

  const int wid = tid >> 6, lane = tid & 63;
#pragma unroll
  for (int i = 0; i < 14; ++i) {
    const float v = wave_sum(i == 0 ? T : A[i - 1]);
    if (lane == 0) red[wid][i] = v;
  }
  __syncthreads();
  if (tid < 14) {
    const float tot = red[0][tid] + red[1][tid] + red[2][tid] + red[3][tid];
    atomicAdd(&ws[WS_T + tid], tot);
  }
}

// -------- fold1: closed-form BN1 stats -> folded conv1 weights ------------
__global__ void k_fold1(const float* __restrict__ g1,
                        const float* __restrict__ be1,
                        const float* __restrict__ w1,
                        const float* __restrict__ b1, float* ws, float NP) {
  const int c = threadIdx.x;
  if (c >= 6) return;
  float Av[13];
#pragma unroll
  for (int i = 0; i < 13; ++i) Av[i] = ws[WS_A + i];
  const float T = ws[WS_T];
  float w[9];
#pragma unroll
  for (int k = 0; k < 9; ++k) w[k] = w1[c * 9 + k];
  float sw = 0.f;
#pragma unroll
  for (int k = 0; k < 9; ++k) sw += w[k];
  float q2 = 0.f;
#pragma unroll
  for (int k1 = 0; k1 < 9; ++k1) {
    const int u1 = k1 / 3, v1 = k1 % 3;
#pragma unroll
    for (int k2 = 0; k2 < 9; ++k2) {
      int du = k2 / 3 - u1, dv = k2 % 3 - v1;
      if (du < 0 || (du == 0 && dv < 0)) { du = -du; dv = -dv; }
      const float a = (du == 0) ? Av[dv] : Av[3 + (du - 1) * 5 + dv + 2];
      q2 = fmaf(w[k1] * w[k2], a, q2);
    }
  }
  const float b = b1[c];
  const float sum1 = sw * T + NP * b;
  const float sumsq1 = q2 + 2.f * b * sw * T + NP * b * b;
  const float mean = sum1 / NP;
  const float var = sumsq1 / NP - mean * mean;
  const float sc = g1[c] * rsqrtf(var + 1e-5f);
  const float sh = be1[c] - mean * sc;
#pragma unroll
  for (int k = 0; k < 9; ++k) ws[WS_W1S + c * 9 + k] = w[k] * sc;
  ws[WS_B1S + c] = fmaf(b, sc, sh);
}

// -------- fold2: BN2 stats -> folded conv2 weights (w2s/b2s) ---------------
__global__ void k_fold2(const float* __restrict__ g2,
                        const float* __restrict__ be2,
                        const float* __restrict__ w2,
                        const float* __restrict__ b2, float* ws, float inv_n) {
  __shared__ float scs[16];
  const int t = threadIdx.x;
  if (t < 16) {
    const float mean = ws[WS_SUM2 + t] * inv_n;
    const float var  = ws[WS_SQ2 + t] * inv_n - mean * mean;
    const float sc   = g2[t] * rsqrtf(var + 1e-5f);
    const float sh   = be2[t] - mean * sc;
    scs[t] = sc;
    ws[WS_B2S + t] = fmaf(b2[t], sc, sh);
  }
  __syncthreads();
  if (t < 384) ws[WS_W2S + t] = w2[t] * scs[t / 24];
}

// ------- Kernel B: conv2 output statistics (+ compact pool store) ----------
__global__ __launch_bounds__(256, 2) void k_stats2(
    const float* __restrict__ x, const float* __restrict__ w2,
    const float* __restrict__ b2, float* ws, float* __restrict__ g_scr,
    int mode) {
  __shared__ __align__(16) float xl[16 * PST];
  __shared__ __align__(16) float pool[16 * POOL_IST];
  __shared__ float red[4][32];
  stage_x(x, xl, blockIdx.x);

  pooled_front_coop(xl, pool, ws);
  __syncthreads();

  const int tid = threadIdx.x;
  if (mode) {  // store compact pool: per image 6ch x (5 rows, stride 6) = 180
    float* gp = g_scr + (size_t)blockIdx.x * TILE_F;
#pragma unroll 1
    for (int i = tid; i < TILE_F; i += 256) {
      const int img = i / GP_IST, rem = i % GP_IST;
      const int c = rem / GP_CST, rr = rem % GP_CST;
      gp[i] = pool[img * POOL_IST + c * POOL_CST + rr];
    }
  }

  float yp[16];
  conv2_lane_t<POOL_CST, POOL_IST>(pool, w2, b2, yp);

  float s = 0.f, q = 0.f;
#pragma unroll
  for (int p = 0; p < 16; ++p) { s += yp[p]; q = fmaf(yp[p], yp[p], q); }
  s += __shfl_xor(s, 16, 64); s += __shfl_xor(s, 32, 64);
  q += __shfl_xor(q, 16, 64); q += __shfl_xor(q, 32, 64);

  const int wid = tid >> 6, lane = tid & 63;
  if (lane < 16) { red[wid][lane] = s; red[wid][16 + lane] = q; }
  __syncthreads();
  if (tid < 32) {
    const float tot = red[0][tid] + red[1][tid] + red[2][tid] + red[3][tid];
    atomicAdd(&ws[tid < 16 ? WS_SUM2 + tid : WS_SQ2 + tid - 16], tot);
  }
}

// -------- shared tail: z (BN2 applied) -> relu-pool -> FC -> out -----------
__device__ __forceinline__ void tail_from_z(
    const float zp[16], const float* __restrict__ fw1,
    const float* __restrict__ fb1, const float* __restrict__ fw2,
    const float* __restrict__ fb2, const float* __restrict__ fw3,
    const float* __restrict__ fb3, float* __restrict__ out, int blk_t,
    float* lds_h, float* lds_a1, float* lds_a2) {
  const int tid = threadIdx.x;
  const int imgl = tid >> 4, al = tid & 15;

  float hq[4] = {0.f, 0.f, 0.f, 0.f};
#pragma unroll
  for (int i2 = 0; i2 < 4; ++i2)
#pragma unroll
    for (int j2 = 0; j2 < 4; ++j2)
      hq[(i2 >> 1) * 2 + (j2 >> 1)] += fmaxf(zp[i2 * 4 + j2], 0.f);
  float4 hv4;
  hv4.x = 0.25f * hq[0]; hv4.y = 0.25f * hq[1];
  hv4.z = 0.25f * hq[2]; hv4.w = 0.25f * hq[3];
  *reinterpret_cast<float4*>(lds_h + imgl * 68 + al * 4) = hv4;
  __syncthreads();

  const float* hrow = lds_h + imgl * 68;
  const bool has2 = (al + 16) < 30;
  float acc0 = fb1[al];
  float acc1 = has2 ? fb1[al + 16] : 0.f;
  const float4* fa = reinterpret_cast<const float4*>(fw1 + al * 64);
  const float4* fb = reinterpret_cast<const float4*>(fw1 + (has2 ? (al + 16) * 64 : 0));
#pragma unroll
  for (int kk = 0; kk < 16; ++kk) {
    const float4 hv = *reinterpret_cast<const float4*>(hrow + kk * 4);
    const float4 wa = fa[kk];
    const float4 wb = fb[kk];
    acc0 = fmaf(wa.x, hv.x, acc0); acc0 = fmaf(wa.y, hv.y, acc0);
    acc0 = fmaf(wa.z, hv.z, acc0); acc0 = fmaf(wa.w, hv.w, acc0);
    acc1 = fmaf(wb.x, hv.x, acc1); acc1 = fmaf(wb.y, hv.y, acc1);
    acc1 = fmaf(wb.z, hv.z, acc1); acc1 = fmaf(wb.w, hv.w, acc1);
  }
  lds_a1[imgl * 33 + al] = fmaxf(acc0, 0.f);
  if (has2) lds_a1[imgl * 33 + al + 16] = fmaxf(acc1, 0.f);
  __syncthreads();

  if (al < 15) {
    float acc = fb2[al];
#pragma unroll 1
    for (int j = 0; j < 30; ++j)
      acc = fmaf(fw2[al * 30 + j], lds_a1[imgl * 33 + j], acc);
    lds_a2[imgl * 17 + al] = fmaxf(acc, 0.f);
  }
  __syncthreads();

  if (al < 10) {
    float acc = fb3[al];
#pragma unroll 1
    for (int j = 0; j < 15; ++j)
      acc = fmaf(fw3[al * 15 + j], lds_a2[imgl * 17 + j], acc);
    out[(size_t)(blk_t * 16 + imgl) * 10 + al] = acc;
  }
}

// ---------------- Kernel C (pool path): 4-tile pipelined -------------------
__global__ __launch_bounds__(256) void k_final_pool(
    const float* __restrict__ g_pool, const float* __restrict__ fw1,
    const float* __restrict__ fb1, const float* __restrict__ fw2,
    const float* __restrict__ fb2, const float* __restrict__ fw3,
    const float* __restrict__ fb3, const float* ws, float* __restrict__ out) {
  __shared__ __align__(16) float pl[TILE_F];
  __shared__ __align__(16) float lds_h[16 * 68];
  __shared__ float lds_a1[16 * 33];
  __shared__ float lds_a2[16 * 17];

  const int tid = threadIdx.x;
  const float4* gp = reinterpret_cast<const float4*>(g_pool);
  float4* pl4 = reinterpret_cast<float4*>(pl);
  const size_t base = (size_t)blockIdx.x * TILES * (TILE_F / 4);

  float4 pf[3];
#pragma unroll
  for (int k = 0; k < 3; ++k) {
    const int i = tid + k * 256;
    if (i < TILE_F / 4) pf[k] = gp[base + i];
  }
#pragma unroll
  for (int k = 0; k < 3; ++k) {
    const int i = tid + k * 256;
    if (i < TILE_F / 4) pl4[i] = pf[k];
  }
  __syncthreads();

#pragma unroll 1
  for (int t = 0; t < TILES; ++t) {
    if (t + 1 < TILES) {  // issue next tile's loads; latency hides under compute
      const size_t nb = base + (size_t)(t + 1) * (TILE_F / 4);
#pragma unroll
      for (int k = 0; k < 3; ++k) {
        const int i = tid + k * 256;
        if (i < TILE_F / 4) pf[k] = gp[nb + i];
      }
    }

    float zp[16];
    conv2_lane_t<GP_CST, GP_IST>(pl, ws + WS_W2S, ws + WS_B2S, zp);
    tail_from_z(zp, fw1, fb1, fw2, fb2, fw3, fb3, out,
                blockIdx.x * TILES + t, lds_h, lds_a1, lds_a2);

    if (t + 1 < TILES) {
      __syncthreads();  // everyone done reading pl (tail syncs cover conv2)
#pragma unroll
      for (int k = 0; k < 3; ++k) {
        const int i = tid + k * 256;
        if (i < TILE_F / 4) pl4[i] = pf[k];
      }
      __syncthreads();
    }
  }
}

// ---------------- Kernel C (recompute fallback) ----------------------------
__global__ __launch_bounds__(256, 2) void k_final_rc(
    const float* __restrict__ x, const float* __restrict__ fw1,
    const float* __restrict__ fb1, const float* __restrict__ fw2,
    const float* __restrict__ fb2, const float* __restrict__ fw3,
    const float* __restrict__ fb3, const float* ws, float* __restrict__ out) {
  __shared__ __align__(16) float xl[16 * PST];
  __shared__ __align__(16) float pool[16 * POOL_IST];
  __shared__ __align__(16) float lds_h[16 * 68];
  __shared__ float lds_a1[16 * 33];
  __shared__ float lds_a2[16 * 17];

  stage_x(x, xl, blockIdx.x);
  pooled_front_coop(xl, pool, ws);
  __syncthreads();

  float zp[16];
  conv2_lane_t<POOL_CST, POOL_IST>(pool, ws + WS_W2S, ws + WS_B2S, zp);
  tail_from_z(zp, fw1, fb1, fw2, fb2, fw3, fb3, out, blockIdx.x,
              lds_h, lds_a1, lds_a2);
}

extern "C" void kernel_launch(void* const* d_in, const int* in_sizes, int n_in,
                              void* d_out, int out_size, void* d_ws, size_t ws_size,
                              hipStream_t stream) {
  (void)n_in; (void)out_size;
  const float* x   = (const float*)d_in[0];
  const float* w1  = (const float*)d_in[1];
  const float* b1  = (const float*)d_in[2];
  const float* g1  = (const float*)d_in[3];
  const float* be1 = (const float*)d_in[4];
  const float* w2  = (const float*)d_in[5];
  const float* b2  = (const float*)d_in[6];
  const float* g2  = (const float*)d_in[7];
  const float* be2 = (const float*)d_in[8];
  const float* fw1 = (const float*)d_in[9];
  const float* fb1 = (const float*)d_in[10];
  const float* fw2 = (const float*)d_in[11];
  const float* fb2 = (const float*)d_in[12];
  const float* fw3 = (const float*)d_in[13];
  const float* fb3 = (const float*)d_in[14];
  float* out = (float*)d_out;
  float* ws  = (float*)d_ws;

  const int Btot = in_sizes[0] / 64;  // 131072; % 16 == 0
  const int nblk = Btot / 16;         // 8192
  const float NP1 = (float)Btot * 100.0f;
  const float inv_n2 = 1.0f / ((float)Btot * 16.0f);

  float* g_scr = ws + WS_SCRATCH;
  const size_t need_pool =
      ((size_t)WS_SCRATCH + (size_t)Btot * GP_IST) * sizeof(float);
  const int mode = (ws_size >= need_pool && (nblk % TILES) == 0) ? 1 : 0;

  hipMemsetAsync(ws, 0, WS_ZERO_N * sizeof(float), stream);

  k_stats1<<<1024, 256, 0, stream>>>(x, ws, nblk);
  k_fold1<<<1, 64, 0, stream>>>(g1, be1, w1, b1, ws, NP1);
  k_stats2<<<nblk, 256, 0, stream>>>(x, w2, b2, ws, g_scr, mode);
  k_fold2<<<1, 512, 0, stream>>>(g2, be2, w2, b2, ws, inv_n2);
  if (mode) {
    k_final_pool<<<nblk / TILES, 256, 0, stream>>>(g_scr, fw1, fb1, fw2, fb2,
                                                   fw3, fb3, ws, out);
  } else {
    k_final_rc<<<nblk, 256, 0, stream>>>(x, fw1, fb1, fw2, fb2, fw3, fb3,
                                         ws, out);
  }
}